// Round 5
// baseline (358.188 us; speedup 1.0000x reference)
//
#include <hip/hip_runtime.h>
#include <stdint.h>

// SymmetricContraction (MACE) on MI355X — symmetrized monomials, 3-kernel split.
//
// out[b,c,m] = sum_{a<=b<=cc} x_a x_b x_cc*T3 + sum_{a<=b} x_a x_b*T2 + sum_a x_a*T1
// Horner: out = sum_a x_a*( T1[a] + sum_{b>=a} x_b*( T2[ab] + sum_{cc>=b} x_cc*T3 ) )
// Irreps fused into float4 slots (0e | 1o m=0..2).
//
// R5 changes (from counters):
//  - sc_build was re-reading 404KB of sym-U per block (517MB L2/L3 ~ 95us).
//    Rewritten: block=(g-chunk,e), thread=c, W in regs, u reads wave-uniform.
//  - sc_apply round-4 global-coef regressed (VMEM latency, VALUBusy 19%).
//    Now: table in LDS (broadcast b128, imm offsets), x in REGISTERS via
//    fully-static template-recursive unroll (all indices compile-time ->
//    SROA, no scratch), 2 nodes packed per lane as float2 -> v_pk_fma_f32.

#define BN 2048
#define CN 128
#define EN 10

#define NT3 816   // #sorted triples a<=b<=cc in [0,16)
#define NT2 136   // #sorted pairs a<=b
#define NTT (NT3 + NT2 + 16)   // 968 fused table entries (float4 each)
#define K3_0 23
#define K3_1 33
#define K2_0 4
#define K2_1 5

// ws layout (float offsets)
#define U3S0_OFF 0                          // [23][816]
#define U3S1_OFF (K3_0*NT3)                 // [3][33][816]
#define U2S0_OFF (U3S1_OFF + 3*K3_1*NT3)    // [4][136]
#define U2S1_OFF (U2S0_OFF + K2_0*NT2)      // [3][5][136]
#define LISTS_OFF (U2S1_OFF + 3*K2_1*NT2)   // int[10][2048]
#define CNT_OFF (LISTS_OFF + EN*BN)         // int[10]
#define TALL_OFF (((CNT_OFF + EN) + 3) & ~3)        // float4[1280][968]
#define WS_NEED_BYTES ((size_t)(TALL_OFF + (size_t)EN*CN*NTT*4) * 4)

#define PREP_TOT (K3_0*NT3 + 3*K3_1*NT3 + K2_0*NT2 + 3*K2_1*NT2)  // 102136
#define PREP_BLOCKS ((PREP_TOT + 255) / 256)                       // 400

typedef float v2f __attribute__((ext_vector_type(2)));

static __device__ __forceinline__ v2f splat2(float v) { v2f r; r.x = v; r.y = v; return r; }
#define FMA2(a, b, c) __builtin_elementwise_fma((a), (b), (c))

constexpr int tri_(int n) { return n * (n + 1) / 2; }
constexpr int rank3(int a, int b, int c) {
    int r = 0;
    for (int i = 0; i < a; ++i) r += tri_(16 - i);
    for (int j = a; j < b; ++j) r += 16 - j;
    return r + (c - b);
}
constexpr int rank2(int a, int b) {
    int r = 0;
    for (int i = 0; i < a; ++i) r += 16 - i;
    return r + (b - a);
}

struct SCState {
    v2f X[16];    // (node0, node1) per i — all accesses constant-indexed
    v2f acc[4];
    v2f tP[4];
    v2f tB[4];
};

// ---- static triangular recursion (all LDS offsets immediate) --------------
template <int A, int B, int C>
struct CL {
    static __device__ __forceinline__ void run(const float4* __restrict__ Ts, SCState& s) {
        const float4 cv = Ts[rank3(A, B, C)];
        s.tB[0] = FMA2(splat2(cv.x), s.X[C], s.tB[0]);
        s.tB[1] = FMA2(splat2(cv.y), s.X[C], s.tB[1]);
        s.tB[2] = FMA2(splat2(cv.z), s.X[C], s.tB[2]);
        s.tB[3] = FMA2(splat2(cv.w), s.X[C], s.tB[3]);
        CL<A, B, C + 1>::run(Ts, s);
    }
};
template <int A, int B>
struct CL<A, B, 16> {
    static __device__ __forceinline__ void run(const float4*, SCState&) {}
};

template <int A, int B>
struct BL {
    static __device__ __forceinline__ void run(const float4* __restrict__ Ts, SCState& s) {
        const float4 c2v = Ts[NT3 + rank2(A, B)];
        s.tB[0] = splat2(c2v.x);
        s.tB[1] = splat2(c2v.y);
        s.tB[2] = splat2(c2v.z);
        s.tB[3] = splat2(c2v.w);
        CL<A, B, B>::run(Ts, s);
        s.tP[0] = FMA2(s.tB[0], s.X[B], s.tP[0]);
        s.tP[1] = FMA2(s.tB[1], s.X[B], s.tP[1]);
        s.tP[2] = FMA2(s.tB[2], s.X[B], s.tP[2]);
        s.tP[3] = FMA2(s.tB[3], s.X[B], s.tP[3]);
        BL<A, B + 1>::run(Ts, s);
    }
};
template <int A>
struct BL<A, 16> {
    static __device__ __forceinline__ void run(const float4*, SCState&) {}
};

template <int A>
struct AL {
    static __device__ __forceinline__ void run(const float4* __restrict__ Ts, SCState& s) {
        const float4 t1v = Ts[NT3 + NT2 + A];
        s.tP[0] = splat2(t1v.x);
        s.tP[1] = splat2(t1v.y);
        s.tP[2] = splat2(t1v.z);
        s.tP[3] = splat2(t1v.w);
        BL<A, A>::run(Ts, s);
        s.acc[0] = FMA2(s.tP[0], s.X[A], s.acc[0]);
        s.acc[1] = FMA2(s.tP[1], s.X[A], s.acc[1]);
        s.acc[2] = FMA2(s.tP[2], s.X[A], s.acc[2]);
        s.acc[3] = FMA2(s.tP[3], s.X[A], s.acc[3]);
        AL<A + 1>::run(Ts, s);
    }
};
template <>
struct AL<16> {
    static __device__ __forceinline__ void run(const float4*, SCState&) {}
};

__global__ __launch_bounds__(256) void prep_sym(
    const float* __restrict__ U3_0, const float* __restrict__ U2_0,
    const float* __restrict__ U3_1, const float* __restrict__ U2_1,
    const float* __restrict__ yg, float* __restrict__ ws)
{
    const int bid = blockIdx.x, tid = threadIdx.x;
    if (bid < PREP_BLOCKS) {
        const int N0 = K3_0*NT3, N1 = 3*K3_1*NT3, P0 = K2_0*NT2;
        const int it = bid*256 + tid;
        if (it >= PREP_TOT) return;
        if (it < N0 + N1) {
            const float* U3; int m, k, K, t, dst;
            if (it < N0) { U3 = U3_0; K = K3_0; m = 0; k = it / NT3; t = it - k*NT3; dst = U3S0_OFF + it; }
            else { int r = it - N0; U3 = U3_1; K = K3_1; int mk = r / NT3; t = r - mk*NT3;
                   m = mk / K3_1; k = mk - m*K3_1; dst = U3S1_OFF + r; }
            // unrank t -> (a<=b<=cc), lexicographic (matches rank3)
            int a = 0, rem = t;
            while (rem >= ((16-a)*(17-a))/2) { rem -= ((16-a)*(17-a))/2; ++a; }
            int b = a;
            while (rem >= 16-b) { rem -= 16-b; ++b; }
            const int cc = b + rem;
            #define AT3(i,j,l) U3[(size_t)(((m*16+(i))*16+(j))*16+(l))*K + k]
            float D = AT3(a,b,cc) + AT3(a,cc,b) + AT3(b,a,cc)
                    + AT3(b,cc,a) + AT3(cc,a,b) + AT3(cc,b,a);
            #undef AT3
            const int eq = (a==b) + (b==cc);
            D *= (eq==2) ? (1.f/6.f) : (eq==1) ? 0.5f : 1.f;
            ws[dst] = D;
        } else {
            const int it2 = it - (N0+N1);
            const float* U2; int m, k, K, pr, dst;
            if (it2 < P0) { U2 = U2_0; K = K2_0; m = 0; k = it2 / NT2; pr = it2 - k*NT2; dst = U2S0_OFF + it2; }
            else { int r = it2 - P0; U2 = U2_1; K = K2_1; int mk = r / NT2; pr = r - mk*NT2;
                   m = mk / K2_1; k = mk - m*K2_1; dst = U2S1_OFF + r; }
            int a = 0, rem = pr;
            while (rem >= 16-a) { rem -= 16-a; ++a; }
            const int b = a + rem;
            float D = U2[(size_t)((m*16+a)*16+b)*K + k]
                    + U2[(size_t)((m*16+b)*16+a)*K + k];
            if (a == b) D *= 0.5f;
            ws[dst] = D;
        }
    } else if (bid < PREP_BLOCKS + EN) {
        const int e = bid - PREP_BLOCKS;
        __shared__ int lcnt;
        if (tid == 0) lcnt = 0;
        __syncthreads();
        int* lists = (int*)(ws + LISTS_OFF);
        for (int b = tid; b < BN; b += 256) {
            if (yg[b*EN + e] > 0.5f) {
                int p = atomicAdd(&lcnt, 1);
                lists[e*BN + p] = b;
            }
        }
        __syncthreads();
        if (tid == 0) ((int*)(ws + CNT_OFF))[e] = lcnt;
    }
}

// ---- fused tables: block=(8-g chunk, e), thread=c. W in regs (coalesced),
// u reads wave-uniform (scalarized, tiny L1 footprint). 968 = 121*8 and the
// region boundaries 816/952 are multiples of 8 -> each block is region-pure.
__global__ __launch_bounds__(128) void sc_build(
    float* __restrict__ ws,
    const float* __restrict__ U1_0, const float* __restrict__ U1_1,
    const float* __restrict__ W3_0, const float* __restrict__ W2_0, const float* __restrict__ W1_0,
    const float* __restrict__ W3_1, const float* __restrict__ W2_1, const float* __restrict__ W1_1)
{
    const int g0 = blockIdx.x * 8;
    const int e = blockIdx.y;
    const int c = threadIdx.x;
    float4* out4 = (float4*)(ws + TALL_OFF) + (size_t)(e*CN + c)*NTT;

    if (g0 < NT3) {
        float w0[K3_0], w1[K3_1];
#pragma unroll
        for (int k = 0; k < K3_0; ++k) w0[k] = W3_0[(e*K3_0 + k)*CN + c];
#pragma unroll
        for (int k = 0; k < K3_1; ++k) w1[k] = W3_1[(e*K3_1 + k)*CN + c];
        const float* u0 = ws + U3S0_OFF;
        const float* u1 = ws + U3S1_OFF;
#pragma unroll 2
        for (int j = 0; j < 8; ++j) {
            const int g = g0 + j;
            float a0 = 0.f, a1 = 0.f, a2 = 0.f, a3 = 0.f;
#pragma unroll
            for (int k = 0; k < K3_0; ++k) a0 = fmaf(u0[k*NT3 + g], w0[k], a0);
#pragma unroll
            for (int k = 0; k < K3_1; ++k) {
                a1 = fmaf(u1[k*NT3 + g], w1[k], a1);
                a2 = fmaf(u1[(K3_1 + k)*NT3 + g], w1[k], a2);
                a3 = fmaf(u1[(2*K3_1 + k)*NT3 + g], w1[k], a3);
            }
            out4[g] = make_float4(a0, a1, a2, a3);
        }
    } else if (g0 < NT3 + NT2) {
        float w0[K2_0], w1[K2_1];
#pragma unroll
        for (int k = 0; k < K2_0; ++k) w0[k] = W2_0[(e*K2_0 + k)*CN + c];
#pragma unroll
        for (int k = 0; k < K2_1; ++k) w1[k] = W2_1[(e*K2_1 + k)*CN + c];
        const float* u0 = ws + U2S0_OFF;
        const float* u1 = ws + U2S1_OFF;
#pragma unroll
        for (int j = 0; j < 8; ++j) {
            const int g = g0 + j;
            const int pr = g - NT3;
            float a0 = 0.f, a1 = 0.f, a2 = 0.f, a3 = 0.f;
#pragma unroll
            for (int k = 0; k < K2_0; ++k) a0 = fmaf(u0[k*NT2 + pr], w0[k], a0);
#pragma unroll
            for (int k = 0; k < K2_1; ++k) {
                a1 = fmaf(u1[k*NT2 + pr], w1[k], a1);
                a2 = fmaf(u1[(K2_1 + k)*NT2 + pr], w1[k], a2);
                a3 = fmaf(u1[(2*K2_1 + k)*NT2 + pr], w1[k], a3);
            }
            out4[g] = make_float4(a0, a1, a2, a3);
        }
    } else {
        const float w10 = W1_0[e*CN + c];
        const float w11 = W1_1[e*CN + c];
#pragma unroll
        for (int j = 0; j < 8; ++j) {
            const int g = g0 + j;
            const int a = g - (NT3 + NT2);
            out4[g] = make_float4(U1_0[a]*w10, U1_1[a]*w11,
                                  U1_1[16+a]*w11, U1_1[32+a]*w11);
        }
    }
}

// ---- node loop: table in LDS (broadcast, imm offsets), x in registers,
// fully static unroll, packed fp32 math. One barrier total.
__global__ __launch_bounds__(128, 3) void sc_apply(
    const float* __restrict__ xg, const float* __restrict__ ws,
    float* __restrict__ outg)
{
    const int c = blockIdx.x, e = blockIdx.y, tid = threadIdx.x;
    __shared__ float4 Ts[NTT];   // 15488 B

    const float4* __restrict__ tG =
        (const float4*)(ws + TALL_OFF) + (size_t)(e*CN + c)*NTT;
    for (int i = tid; i < NTT; i += 128) Ts[i] = tG[i];

    const int* lists = (const int*)(ws + LISTS_OFF) + e*BN;
    const int cnt = ((const int*)(ws + CNT_OFF))[e];
    __syncthreads();

    for (int base = 0; base < cnt; base += 256) {
        const int s0 = base + tid, s1 = base + tid + 128;
        const bool act0 = s0 < cnt, act1 = s1 < cnt;
        const int n0 = lists[act0 ? s0 : 0];
        const int n1 = lists[act1 ? s1 : 0];
        const float4* p0 = (const float4*)(xg + ((size_t)n0*CN + c)*16);
        const float4* p1 = (const float4*)(xg + ((size_t)n1*CN + c)*16);

        SCState s;
#pragma unroll
        for (int d = 0; d < 4; ++d) {
            const float4 v0 = p0[d];
            const float4 v1 = p1[d];
            s.X[4*d+0].x = v0.x; s.X[4*d+0].y = v1.x;
            s.X[4*d+1].x = v0.y; s.X[4*d+1].y = v1.y;
            s.X[4*d+2].x = v0.z; s.X[4*d+2].y = v1.z;
            s.X[4*d+3].x = v0.w; s.X[4*d+3].y = v1.w;
        }
        s.acc[0] = splat2(0.f); s.acc[1] = splat2(0.f);
        s.acc[2] = splat2(0.f); s.acc[3] = splat2(0.f);

        AL<0>::run(Ts, s);

        if (act0) {
            float* o = outg + (size_t)n0*512;
            o[c] = s.acc[0].x;
            o[128 + c*3 + 0] = s.acc[1].x;
            o[128 + c*3 + 1] = s.acc[2].x;
            o[128 + c*3 + 2] = s.acc[3].x;
        }
        if (act1) {
            float* o = outg + (size_t)n1*512;
            o[c] = s.acc[0].y;
            o[128 + c*3 + 0] = s.acc[1].y;
            o[128 + c*3 + 1] = s.acc[2].y;
            o[128 + c*3 + 2] = s.acc[3].y;
        }
    }
}

// ---- fallback (proven fused kernel): used only if ws is too small ---------
__global__ __launch_bounds__(128) void sc_main_fused(
    const float* __restrict__ xg,
    const float* __restrict__ U1_0, const float* __restrict__ U1_1,
    const float* __restrict__ W3_0, const float* __restrict__ W2_0, const float* __restrict__ W1_0,
    const float* __restrict__ W3_1, const float* __restrict__ W2_1, const float* __restrict__ W1_1,
    const float* __restrict__ ws, float* __restrict__ outg)
{
    const int c = blockIdx.x, e = blockIdx.y, tid = threadIdx.x;
    __shared__ float4 T3s[NT3];
    __shared__ float4 T2s[NT2];
    __shared__ float4 T1s[16];
    __shared__ float xs0[16*128];
    __shared__ float xs1[16*128];
    __shared__ float wk30s[K3_0], wk31s[K3_1], wk20s[K2_0], wk21s[K2_1];

    if (tid < K3_0) wk30s[tid] = W3_0[(e*K3_0 + tid)*CN + c];
    if (tid >= 32 && tid < 32 + K3_1) wk31s[tid-32] = W3_1[(e*K3_1 + (tid-32))*CN + c];
    if (tid >= 72 && tid < 72 + K2_0) wk20s[tid-72] = W2_0[(e*K2_0 + (tid-72))*CN + c];
    if (tid >= 80 && tid < 80 + K2_1) wk21s[tid-80] = W2_1[(e*K2_1 + (tid-80))*CN + c];
    __syncthreads();

    const float* u3s0 = ws + U3S0_OFF;
    const float* u3s1 = ws + U3S1_OFF;
    for (int g = tid; g < NT3/4; g += 128) {
        float4 A0 = make_float4(0,0,0,0), A1 = A0, A2 = A0, A3 = A0;
#pragma unroll
        for (int k = 0; k < K3_0; ++k) {
            const float w = wk30s[k];
            const float4 u = ((const float4*)(u3s0 + k*NT3))[g];
            A0.x = fmaf(u.x, w, A0.x); A0.y = fmaf(u.y, w, A0.y);
            A0.z = fmaf(u.z, w, A0.z); A0.w = fmaf(u.w, w, A0.w);
        }
#pragma unroll 8
        for (int k = 0; k < K3_1; ++k) {
            const float w = wk31s[k];
            const float4 ua = ((const float4*)(u3s1 + k*NT3))[g];
            A1.x = fmaf(ua.x, w, A1.x); A1.y = fmaf(ua.y, w, A1.y);
            A1.z = fmaf(ua.z, w, A1.z); A1.w = fmaf(ua.w, w, A1.w);
            const float4 ub = ((const float4*)(u3s1 + (K3_1 + k)*NT3))[g];
            A2.x = fmaf(ub.x, w, A2.x); A2.y = fmaf(ub.y, w, A2.y);
            A2.z = fmaf(ub.z, w, A2.z); A2.w = fmaf(ub.w, w, A2.w);
            const float4 uc = ((const float4*)(u3s1 + (2*K3_1 + k)*NT3))[g];
            A3.x = fmaf(uc.x, w, A3.x); A3.y = fmaf(uc.y, w, A3.y);
            A3.z = fmaf(uc.z, w, A3.z); A3.w = fmaf(uc.w, w, A3.w);
        }
        T3s[4*g+0] = make_float4(A0.x, A1.x, A2.x, A3.x);
        T3s[4*g+1] = make_float4(A0.y, A1.y, A2.y, A3.y);
        T3s[4*g+2] = make_float4(A0.z, A1.z, A2.z, A3.z);
        T3s[4*g+3] = make_float4(A0.w, A1.w, A2.w, A3.w);
    }
    const float* u2s0 = ws + U2S0_OFF;
    const float* u2s1 = ws + U2S1_OFF;
    for (int g = tid; g < NT2/4; g += 128) {
        float4 A0 = make_float4(0,0,0,0), A1 = A0, A2 = A0, A3 = A0;
#pragma unroll
        for (int k = 0; k < K2_0; ++k) {
            const float w = wk20s[k];
            const float4 u = ((const float4*)(u2s0 + k*NT2))[g];
            A0.x = fmaf(u.x, w, A0.x); A0.y = fmaf(u.y, w, A0.y);
            A0.z = fmaf(u.z, w, A0.z); A0.w = fmaf(u.w, w, A0.w);
        }
#pragma unroll
        for (int k = 0; k < K2_1; ++k) {
            const float w = wk21s[k];
            const float4 ua = ((const float4*)(u2s1 + k*NT2))[g];
            A1.x = fmaf(ua.x, w, A1.x); A1.y = fmaf(ua.y, w, A1.y);
            A1.z = fmaf(ua.z, w, A1.z); A1.w = fmaf(ua.w, w, A1.w);
            const float4 ub = ((const float4*)(u2s1 + (K2_1 + k)*NT2))[g];
            A2.x = fmaf(ub.x, w, A2.x); A2.y = fmaf(ub.y, w, A2.y);
            A2.z = fmaf(ub.z, w, A2.z); A2.w = fmaf(ub.w, w, A2.w);
            const float4 uc = ((const float4*)(u2s1 + (2*K2_1 + k)*NT2))[g];
            A3.x = fmaf(uc.x, w, A3.x); A3.y = fmaf(uc.y, w, A3.y);
            A3.z = fmaf(uc.z, w, A3.z); A3.w = fmaf(uc.w, w, A3.w);
        }
        T2s[4*g+0] = make_float4(A0.x, A1.x, A2.x, A3.x);
        T2s[4*g+1] = make_float4(A0.y, A1.y, A2.y, A3.y);
        T2s[4*g+2] = make_float4(A0.z, A1.z, A2.z, A3.z);
        T2s[4*g+3] = make_float4(A0.w, A1.w, A2.w, A3.w);
    }
    if (tid < 16) {
        const float wk10 = W1_0[e*CN + c];
        const float wk11 = W1_1[e*CN + c];
        const int j = tid;
        T1s[j] = make_float4(U1_0[j]*wk10, U1_1[j]*wk11,
                             U1_1[16+j]*wk11, U1_1[32+j]*wk11);
    }

    const int* lists = (const int*)(ws + LISTS_OFF) + e*BN;
    const int cnt = ((const int*)(ws + CNT_OFF))[e];
    __syncthreads();

    for (int base = 0; base < cnt; base += 256) {
        const int s0 = base + tid, s1 = base + tid + 128;
        const bool act0 = s0 < cnt, act1 = s1 < cnt;
        const int n0 = lists[act0 ? s0 : 0];
        const int n1 = lists[act1 ? s1 : 0];
        const float4* p0 = (const float4*)(xg + ((size_t)n0*CN + c)*16);
        const float4* p1 = (const float4*)(xg + ((size_t)n1*CN + c)*16);
#pragma unroll
        for (int d = 0; d < 4; ++d) {
            const float4 v0 = p0[d]; const float4 v1 = p1[d];
            xs0[(4*d+0)*128+tid] = v0.x; xs0[(4*d+1)*128+tid] = v0.y;
            xs0[(4*d+2)*128+tid] = v0.z; xs0[(4*d+3)*128+tid] = v0.w;
            xs1[(4*d+0)*128+tid] = v1.x; xs1[(4*d+1)*128+tid] = v1.y;
            xs1[(4*d+2)*128+tid] = v1.z; xs1[(4*d+3)*128+tid] = v1.w;
        }
        float4 acc0 = make_float4(0,0,0,0), acc1 = acc0;
        int t3 = 0, t2i = 0;
#pragma unroll 1
        for (int a = 0; a < 16; ++a) {
            const float xa0 = xs0[a*128+tid];
            const float xa1 = xs1[a*128+tid];
            float4 tP0 = T1s[a], tP1 = tP0;
#pragma unroll 1
            for (int b = a; b < 16; ++b) {
                const float xb0 = xs0[b*128+tid];
                const float xb1 = xs1[b*128+tid];
                const float4 c2v = T2s[t2i]; ++t2i;
                float4 tB0 = c2v, tB1 = c2v;
#pragma unroll 4
                for (int cc = b; cc < 16; ++cc) {
                    const float xc0 = xs0[cc*128+tid];
                    const float xc1 = xs1[cc*128+tid];
                    const float4 c3v = T3s[t3]; ++t3;
                    tB0.x = fmaf(c3v.x, xc0, tB0.x); tB0.y = fmaf(c3v.y, xc0, tB0.y);
                    tB0.z = fmaf(c3v.z, xc0, tB0.z); tB0.w = fmaf(c3v.w, xc0, tB0.w);
                    tB1.x = fmaf(c3v.x, xc1, tB1.x); tB1.y = fmaf(c3v.y, xc1, tB1.y);
                    tB1.z = fmaf(c3v.z, xc1, tB1.z); tB1.w = fmaf(c3v.w, xc1, tB1.w);
                }
                tP0.x = fmaf(tB0.x, xb0, tP0.x); tP0.y = fmaf(tB0.y, xb0, tP0.y);
                tP0.z = fmaf(tB0.z, xb0, tP0.z); tP0.w = fmaf(tB0.w, xb0, tP0.w);
                tP1.x = fmaf(tB1.x, xb1, tP1.x); tP1.y = fmaf(tB1.y, xb1, tP1.y);
                tP1.z = fmaf(tB1.z, xb1, tP1.z); tP1.w = fmaf(tB1.w, xb1, tP1.w);
            }
            acc0.x = fmaf(tP0.x, xa0, acc0.x); acc0.y = fmaf(tP0.y, xa0, acc0.y);
            acc0.z = fmaf(tP0.z, xa0, acc0.z); acc0.w = fmaf(tP0.w, xa0, acc0.w);
            acc1.x = fmaf(tP1.x, xa1, acc1.x); acc1.y = fmaf(tP1.y, xa1, acc1.y);
            acc1.z = fmaf(tP1.z, xa1, acc1.z); acc1.w = fmaf(tP1.w, xa1, acc1.w);
        }
        if (act0) {
            float* o = outg + (size_t)n0*512;
            o[c] = acc0.x;
            o[128 + c*3 + 0] = acc0.y; o[128 + c*3 + 1] = acc0.z; o[128 + c*3 + 2] = acc0.w;
        }
        if (act1) {
            float* o = outg + (size_t)n1*512;
            o[c] = acc1.x;
            o[128 + c*3 + 0] = acc1.y; o[128 + c*3 + 1] = acc1.z; o[128 + c*3 + 2] = acc1.w;
        }
    }
}

extern "C" void kernel_launch(void* const* d_in, const int* in_sizes, int n_in,
                              void* d_out, int out_size, void* d_ws, size_t ws_size,
                              hipStream_t stream) {
    const float* x = (const float*)d_in[0];
    const float* y = (const float*)d_in[1];
    const float* U3_0 = (const float*)d_in[2];
    const float* U2_0 = (const float*)d_in[3];
    const float* U1_0 = (const float*)d_in[4];
    const float* W3_0 = (const float*)d_in[5];
    const float* W2_0 = (const float*)d_in[6];
    const float* W1_0 = (const float*)d_in[7];
    const float* U3_1 = (const float*)d_in[8];
    const float* U2_1 = (const float*)d_in[9];
    const float* U1_1 = (const float*)d_in[10];
    const float* W3_1 = (const float*)d_in[11];
    const float* W2_1 = (const float*)d_in[12];
    const float* W1_1 = (const float*)d_in[13];
    float* out = (float*)d_out;
    float* ws = (float*)d_ws;

    prep_sym<<<dim3(PREP_BLOCKS + EN), 256, 0, stream>>>(U3_0, U2_0, U3_1, U2_1, y, ws);
    if (ws_size >= WS_NEED_BYTES) {
        sc_build<<<dim3(NTT/8, EN), 128, 0, stream>>>(ws, U1_0, U1_1,
                                                      W3_0, W2_0, W1_0, W3_1, W2_1, W1_1);
        sc_apply<<<dim3(CN, EN), 128, 0, stream>>>(x, ws, out);
    } else {
        sc_main_fused<<<dim3(CN, EN), 128, 0, stream>>>(x, U1_0, U1_1,
                                                        W3_0, W2_0, W1_0,
                                                        W3_1, W2_1, W1_1, ws, out);
    }
}

// Round 6
// 198.437 us; speedup vs baseline: 1.8051x; 1.8051x over previous
//
#include <hip/hip_runtime.h>
#include <stdint.h>

// SymmetricContraction (MACE) on MI355X — symmetrized monomials, 3-kernel split.
//
// out[b,c,m] = sum_{a<=b<=cc} x_a x_b x_cc*T3 + sum_{a<=b} x_a x_b*T2 + sum_a x_a*T1
// Horner: out = sum_a x_a*( T1[a] + sum_{b>=a} x_b*( T2[ab] + sum_{cc>=b} x_cc*T3 ) )
// Irreps fused into float4 slots (0e | 1o m=0..2).
//
// R6 (from counters):
//  - R5's full-static unroll blew I-cache (~96KB body) + scratch (341MB writes).
//    Back to R3's runtime triangular loops (proven 84us, zero scratch).
//  - sc_apply was LDS-pipe-bound (968 b128 coef + 1936 b32 x per wave-pass).
//    Now: 2 nodes packed as float2 in LDS -> ONE ds_read_b64 per x access
//    (1936 total LDS ops/wave, -33%), and packed v_pk_fma_f32 math (v2f +
//    __builtin_elementwise_fma) halves FMA issue.
//  - sc_build: sym-U reads and table writes passed as disjoint __restrict__
//    pointers so uniform u-reads can scalarize (s_load, off the VMEM pipe).

#define BN 2048
#define CN 128
#define EN 10

#define NT3 816   // #sorted triples a<=b<=cc in [0,16)
#define NT2 136   // #sorted pairs a<=b
#define NTT (NT3 + NT2 + 16)   // 968 fused table entries (float4 each)
#define K3_0 23
#define K3_1 33
#define K2_0 4
#define K2_1 5

// ws layout (float offsets)
#define U3S0_OFF 0                          // [23][816]
#define U3S1_OFF (K3_0*NT3)                 // [3][33][816]
#define U2S0_OFF (U3S1_OFF + 3*K3_1*NT3)    // [4][136]
#define U2S1_OFF (U2S0_OFF + K2_0*NT2)      // [3][5][136]
#define LISTS_OFF (U2S1_OFF + 3*K2_1*NT2)   // int[10][2048]
#define CNT_OFF (LISTS_OFF + EN*BN)         // int[10]
#define TALL_OFF (((CNT_OFF + EN) + 3) & ~3)        // float4[1280][968]
#define WS_NEED_BYTES ((size_t)(TALL_OFF + (size_t)EN*CN*NTT*4) * 4)

#define PREP_TOT (K3_0*NT3 + 3*K3_1*NT3 + K2_0*NT2 + 3*K2_1*NT2)  // 102136
#define PREP_BLOCKS ((PREP_TOT + 255) / 256)                       // 400

typedef float v2f __attribute__((ext_vector_type(2)));
#define FMA2(a, b, c) __builtin_elementwise_fma((a), (b), (c))
static __device__ __forceinline__ v2f splat2(float v) { v2f r; r.x = v; r.y = v; return r; }

__global__ __launch_bounds__(256) void prep_sym(
    const float* __restrict__ U3_0, const float* __restrict__ U2_0,
    const float* __restrict__ U3_1, const float* __restrict__ U2_1,
    const float* __restrict__ yg, float* __restrict__ ws)
{
    const int bid = blockIdx.x, tid = threadIdx.x;
    if (bid < PREP_BLOCKS) {
        const int N0 = K3_0*NT3, N1 = 3*K3_1*NT3, P0 = K2_0*NT2;
        const int it = bid*256 + tid;
        if (it >= PREP_TOT) return;
        if (it < N0 + N1) {
            const float* U3; int m, k, K, t, dst;
            if (it < N0) { U3 = U3_0; K = K3_0; m = 0; k = it / NT3; t = it - k*NT3; dst = U3S0_OFF + it; }
            else { int r = it - N0; U3 = U3_1; K = K3_1; int mk = r / NT3; t = r - mk*NT3;
                   m = mk / K3_1; k = mk - m*K3_1; dst = U3S1_OFF + r; }
            // unrank t -> (a<=b<=cc), lexicographic (matches sc_apply loop order)
            int a = 0, rem = t;
            while (rem >= ((16-a)*(17-a))/2) { rem -= ((16-a)*(17-a))/2; ++a; }
            int b = a;
            while (rem >= 16-b) { rem -= 16-b; ++b; }
            const int cc = b + rem;
            #define AT3(i,j,l) U3[(size_t)(((m*16+(i))*16+(j))*16+(l))*K + k]
            float D = AT3(a,b,cc) + AT3(a,cc,b) + AT3(b,a,cc)
                    + AT3(b,cc,a) + AT3(cc,a,b) + AT3(cc,b,a);
            #undef AT3
            const int eq = (a==b) + (b==cc);
            D *= (eq==2) ? (1.f/6.f) : (eq==1) ? 0.5f : 1.f;
            ws[dst] = D;
        } else {
            const int it2 = it - (N0+N1);
            const float* U2; int m, k, K, pr, dst;
            if (it2 < P0) { U2 = U2_0; K = K2_0; m = 0; k = it2 / NT2; pr = it2 - k*NT2; dst = U2S0_OFF + it2; }
            else { int r = it2 - P0; U2 = U2_1; K = K2_1; int mk = r / NT2; pr = r - mk*NT2;
                   m = mk / K2_1; k = mk - m*K2_1; dst = U2S1_OFF + r; }
            int a = 0, rem = pr;
            while (rem >= 16-a) { rem -= 16-a; ++a; }
            const int b = a + rem;
            float D = U2[(size_t)((m*16+a)*16+b)*K + k]
                    + U2[(size_t)((m*16+b)*16+a)*K + k];
            if (a == b) D *= 0.5f;
            ws[dst] = D;
        }
    } else if (bid < PREP_BLOCKS + EN) {
        const int e = bid - PREP_BLOCKS;
        __shared__ int lcnt;
        if (tid == 0) lcnt = 0;
        __syncthreads();
        int* lists = (int*)(ws + LISTS_OFF);
        for (int b = tid; b < BN; b += 256) {
            if (yg[b*EN + e] > 0.5f) {
                int p = atomicAdd(&lcnt, 1);
                lists[e*BN + p] = b;
            }
        }
        __syncthreads();
        if (tid == 0) ((int*)(ws + CNT_OFF))[e] = lcnt;
    }
}

// ---- fused tables: block=(8-g chunk, e), thread=c. W in regs (coalesced),
// u reads wave-uniform; usym/tall are DISJOINT ws regions passed as separate
// __restrict__ pointers so the uniform reads can scalarize.
__global__ __launch_bounds__(128) void sc_build(
    const float* __restrict__ usym, float4* __restrict__ tall,
    const float* __restrict__ U1_0, const float* __restrict__ U1_1,
    const float* __restrict__ W3_0, const float* __restrict__ W2_0, const float* __restrict__ W1_0,
    const float* __restrict__ W3_1, const float* __restrict__ W2_1, const float* __restrict__ W1_1)
{
    const int g0 = blockIdx.x * 8;
    const int e = blockIdx.y;
    const int c = threadIdx.x;
    float4* out4 = tall + (size_t)(e*CN + c)*NTT;

    if (g0 < NT3) {
        float w0[K3_0], w1[K3_1];
#pragma unroll
        for (int k = 0; k < K3_0; ++k) w0[k] = W3_0[(e*K3_0 + k)*CN + c];
#pragma unroll
        for (int k = 0; k < K3_1; ++k) w1[k] = W3_1[(e*K3_1 + k)*CN + c];
        const float* u0 = usym + U3S0_OFF;
        const float* u1 = usym + U3S1_OFF;
#pragma unroll 2
        for (int j = 0; j < 8; ++j) {
            const int g = g0 + j;
            float a0 = 0.f, a1 = 0.f, a2 = 0.f, a3 = 0.f;
#pragma unroll
            for (int k = 0; k < K3_0; ++k) a0 = fmaf(u0[k*NT3 + g], w0[k], a0);
#pragma unroll
            for (int k = 0; k < K3_1; ++k) {
                a1 = fmaf(u1[k*NT3 + g], w1[k], a1);
                a2 = fmaf(u1[(K3_1 + k)*NT3 + g], w1[k], a2);
                a3 = fmaf(u1[(2*K3_1 + k)*NT3 + g], w1[k], a3);
            }
            out4[g] = make_float4(a0, a1, a2, a3);
        }
    } else if (g0 < NT3 + NT2) {
        float w0[K2_0], w1[K2_1];
#pragma unroll
        for (int k = 0; k < K2_0; ++k) w0[k] = W2_0[(e*K2_0 + k)*CN + c];
#pragma unroll
        for (int k = 0; k < K2_1; ++k) w1[k] = W2_1[(e*K2_1 + k)*CN + c];
        const float* u0 = usym + U2S0_OFF;
        const float* u1 = usym + U2S1_OFF;
#pragma unroll
        for (int j = 0; j < 8; ++j) {
            const int g = g0 + j;
            const int pr = g - NT3;
            float a0 = 0.f, a1 = 0.f, a2 = 0.f, a3 = 0.f;
#pragma unroll
            for (int k = 0; k < K2_0; ++k) a0 = fmaf(u0[k*NT2 + pr], w0[k], a0);
#pragma unroll
            for (int k = 0; k < K2_1; ++k) {
                a1 = fmaf(u1[k*NT2 + pr], w1[k], a1);
                a2 = fmaf(u1[(K2_1 + k)*NT2 + pr], w1[k], a2);
                a3 = fmaf(u1[(2*K2_1 + k)*NT2 + pr], w1[k], a3);
            }
            out4[g] = make_float4(a0, a1, a2, a3);
        }
    } else {
        const float w10 = W1_0[e*CN + c];
        const float w11 = W1_1[e*CN + c];
#pragma unroll
        for (int j = 0; j < 8; ++j) {
            const int g = g0 + j;
            const int a = g - (NT3 + NT2);
            out4[g] = make_float4(U1_0[a]*w10, U1_1[a]*w11,
                                  U1_1[16+a]*w11, U1_1[32+a]*w11);
        }
    }
}

// ---- node loop: table in LDS (b128 broadcast), 2 nodes packed per lane as
// float2 in LDS (single ds_read_b64 per x access), packed v_pk_fma math.
__global__ __launch_bounds__(128) void sc_apply(
    const float* __restrict__ xg, const float* __restrict__ ws,
    float* __restrict__ outg)
{
    const int c = blockIdx.x, e = blockIdx.y, tid = threadIdx.x;
    __shared__ float4 Ts[NTT];     // 15488 B
    __shared__ v2f xs[16*128];     // 16384 B: row i, pair column per thread

    const float4* __restrict__ tG =
        (const float4*)(ws + TALL_OFF) + (size_t)(e*CN + c)*NTT;
    for (int i = tid; i < NTT; i += 128) Ts[i] = tG[i];

    const int* lists = (const int*)(ws + LISTS_OFF) + e*BN;
    const int cnt = ((const int*)(ws + CNT_OFF))[e];
    __syncthreads();

    for (int base = 0; base < cnt; base += 256) {
        const int s0 = base + tid, s1 = base + tid + 128;
        const bool act0 = s0 < cnt, act1 = s1 < cnt;
        const int n0 = lists[act0 ? s0 : 0];
        const int n1 = lists[act1 ? s1 : 0];
        const float4* p0 = (const float4*)(xg + ((size_t)n0*CN + c)*16);
        const float4* p1 = (const float4*)(xg + ((size_t)n1*CN + c)*16);
#pragma unroll
        for (int d = 0; d < 4; ++d) {
            const float4 v0 = p0[d]; const float4 v1 = p1[d];
            v2f w;
            w.x = v0.x; w.y = v1.x; xs[(4*d+0)*128+tid] = w;
            w.x = v0.y; w.y = v1.y; xs[(4*d+1)*128+tid] = w;
            w.x = v0.z; w.y = v1.z; xs[(4*d+2)*128+tid] = w;
            w.x = v0.w; w.y = v1.w; xs[(4*d+3)*128+tid] = w;
        }
        // xs columns are thread-private: no barrier anywhere.

        v2f acc0 = splat2(0.f), acc1 = acc0, acc2 = acc0, acc3 = acc0;
        int t3 = 0, t2 = NT3;
#pragma unroll 1
        for (int a = 0; a < 16; ++a) {
            const v2f xa = xs[a*128+tid];
            const float4 t1v = Ts[NT3 + NT2 + a];
            v2f tP0 = splat2(t1v.x), tP1 = splat2(t1v.y),
                tP2 = splat2(t1v.z), tP3 = splat2(t1v.w);
#pragma unroll 1
            for (int b = a; b < 16; ++b) {
                const v2f xb = xs[b*128+tid];
                const float4 c2v = Ts[t2]; ++t2;
                v2f tB0 = splat2(c2v.x), tB1 = splat2(c2v.y),
                    tB2 = splat2(c2v.z), tB3 = splat2(c2v.w);
#pragma unroll 4
                for (int cc = b; cc < 16; ++cc) {
                    const v2f xc = xs[cc*128+tid];
                    const float4 c3v = Ts[t3]; ++t3;
                    tB0 = FMA2(splat2(c3v.x), xc, tB0);
                    tB1 = FMA2(splat2(c3v.y), xc, tB1);
                    tB2 = FMA2(splat2(c3v.z), xc, tB2);
                    tB3 = FMA2(splat2(c3v.w), xc, tB3);
                }
                tP0 = FMA2(tB0, xb, tP0);
                tP1 = FMA2(tB1, xb, tP1);
                tP2 = FMA2(tB2, xb, tP2);
                tP3 = FMA2(tB3, xb, tP3);
            }
            acc0 = FMA2(tP0, xa, acc0);
            acc1 = FMA2(tP1, xa, acc1);
            acc2 = FMA2(tP2, xa, acc2);
            acc3 = FMA2(tP3, xa, acc3);
        }
        if (act0) {
            float* o = outg + (size_t)n0*512;
            o[c] = acc0.x;
            o[128 + c*3 + 0] = acc1.x; o[128 + c*3 + 1] = acc2.x; o[128 + c*3 + 2] = acc3.x;
        }
        if (act1) {
            float* o = outg + (size_t)n1*512;
            o[c] = acc0.y;
            o[128 + c*3 + 0] = acc1.y; o[128 + c*3 + 1] = acc2.y; o[128 + c*3 + 2] = acc3.y;
        }
    }
}

// ---- fallback (proven fused kernel): used only if ws is too small ---------
__global__ __launch_bounds__(128) void sc_main_fused(
    const float* __restrict__ xg,
    const float* __restrict__ U1_0, const float* __restrict__ U1_1,
    const float* __restrict__ W3_0, const float* __restrict__ W2_0, const float* __restrict__ W1_0,
    const float* __restrict__ W3_1, const float* __restrict__ W2_1, const float* __restrict__ W1_1,
    const float* __restrict__ ws, float* __restrict__ outg)
{
    const int c = blockIdx.x, e = blockIdx.y, tid = threadIdx.x;
    __shared__ float4 T3s[NT3];
    __shared__ float4 T2s[NT2];
    __shared__ float4 T1s[16];
    __shared__ float xs0[16*128];
    __shared__ float xs1[16*128];
    __shared__ float wk30s[K3_0], wk31s[K3_1], wk20s[K2_0], wk21s[K2_1];

    if (tid < K3_0) wk30s[tid] = W3_0[(e*K3_0 + tid)*CN + c];
    if (tid >= 32 && tid < 32 + K3_1) wk31s[tid-32] = W3_1[(e*K3_1 + (tid-32))*CN + c];
    if (tid >= 72 && tid < 72 + K2_0) wk20s[tid-72] = W2_0[(e*K2_0 + (tid-72))*CN + c];
    if (tid >= 80 && tid < 80 + K2_1) wk21s[tid-80] = W2_1[(e*K2_1 + (tid-80))*CN + c];
    __syncthreads();

    const float* u3s0 = ws + U3S0_OFF;
    const float* u3s1 = ws + U3S1_OFF;
    for (int g = tid; g < NT3/4; g += 128) {
        float4 A0 = make_float4(0,0,0,0), A1 = A0, A2 = A0, A3 = A0;
#pragma unroll
        for (int k = 0; k < K3_0; ++k) {
            const float w = wk30s[k];
            const float4 u = ((const float4*)(u3s0 + k*NT3))[g];
            A0.x = fmaf(u.x, w, A0.x); A0.y = fmaf(u.y, w, A0.y);
            A0.z = fmaf(u.z, w, A0.z); A0.w = fmaf(u.w, w, A0.w);
        }
#pragma unroll 8
        for (int k = 0; k < K3_1; ++k) {
            const float w = wk31s[k];
            const float4 ua = ((const float4*)(u3s1 + k*NT3))[g];
            A1.x = fmaf(ua.x, w, A1.x); A1.y = fmaf(ua.y, w, A1.y);
            A1.z = fmaf(ua.z, w, A1.z); A1.w = fmaf(ua.w, w, A1.w);
            const float4 ub = ((const float4*)(u3s1 + (K3_1 + k)*NT3))[g];
            A2.x = fmaf(ub.x, w, A2.x); A2.y = fmaf(ub.y, w, A2.y);
            A2.z = fmaf(ub.z, w, A2.z); A2.w = fmaf(ub.w, w, A2.w);
            const float4 uc = ((const float4*)(u3s1 + (2*K3_1 + k)*NT3))[g];
            A3.x = fmaf(uc.x, w, A3.x); A3.y = fmaf(uc.y, w, A3.y);
            A3.z = fmaf(uc.z, w, A3.z); A3.w = fmaf(uc.w, w, A3.w);
        }
        T3s[4*g+0] = make_float4(A0.x, A1.x, A2.x, A3.x);
        T3s[4*g+1] = make_float4(A0.y, A1.y, A2.y, A3.y);
        T3s[4*g+2] = make_float4(A0.z, A1.z, A2.z, A3.z);
        T3s[4*g+3] = make_float4(A0.w, A1.w, A2.w, A3.w);
    }
    const float* u2s0 = ws + U2S0_OFF;
    const float* u2s1 = ws + U2S1_OFF;
    for (int g = tid; g < NT2/4; g += 128) {
        float4 A0 = make_float4(0,0,0,0), A1 = A0, A2 = A0, A3 = A0;
#pragma unroll
        for (int k = 0; k < K2_0; ++k) {
            const float w = wk20s[k];
            const float4 u = ((const float4*)(u2s0 + k*NT2))[g];
            A0.x = fmaf(u.x, w, A0.x); A0.y = fmaf(u.y, w, A0.y);
            A0.z = fmaf(u.z, w, A0.z); A0.w = fmaf(u.w, w, A0.w);
        }
#pragma unroll
        for (int k = 0; k < K2_1; ++k) {
            const float w = wk21s[k];
            const float4 ua = ((const float4*)(u2s1 + k*NT2))[g];
            A1.x = fmaf(ua.x, w, A1.x); A1.y = fmaf(ua.y, w, A1.y);
            A1.z = fmaf(ua.z, w, A1.z); A1.w = fmaf(ua.w, w, A1.w);
            const float4 ub = ((const float4*)(u2s1 + (K2_1 + k)*NT2))[g];
            A2.x = fmaf(ub.x, w, A2.x); A2.y = fmaf(ub.y, w, A2.y);
            A2.z = fmaf(ub.z, w, A2.z); A2.w = fmaf(ub.w, w, A2.w);
            const float4 uc = ((const float4*)(u2s1 + (2*K2_1 + k)*NT2))[g];
            A3.x = fmaf(uc.x, w, A3.x); A3.y = fmaf(uc.y, w, A3.y);
            A3.z = fmaf(uc.z, w, A3.z); A3.w = fmaf(uc.w, w, A3.w);
        }
        T2s[4*g+0] = make_float4(A0.x, A1.x, A2.x, A3.x);
        T2s[4*g+1] = make_float4(A0.y, A1.y, A2.y, A3.y);
        T2s[4*g+2] = make_float4(A0.z, A1.z, A2.z, A3.z);
        T2s[4*g+3] = make_float4(A0.w, A1.w, A2.w, A3.w);
    }
    if (tid < 16) {
        const float wk10 = W1_0[e*CN + c];
        const float wk11 = W1_1[e*CN + c];
        const int j = tid;
        T1s[j] = make_float4(U1_0[j]*wk10, U1_1[j]*wk11,
                             U1_1[16+j]*wk11, U1_1[32+j]*wk11);
    }

    const int* lists = (const int*)(ws + LISTS_OFF) + e*BN;
    const int cnt = ((const int*)(ws + CNT_OFF))[e];
    __syncthreads();

    for (int base = 0; base < cnt; base += 256) {
        const int s0 = base + tid, s1 = base + tid + 128;
        const bool act0 = s0 < cnt, act1 = s1 < cnt;
        const int n0 = lists[act0 ? s0 : 0];
        const int n1 = lists[act1 ? s1 : 0];
        const float4* p0 = (const float4*)(xg + ((size_t)n0*CN + c)*16);
        const float4* p1 = (const float4*)(xg + ((size_t)n1*CN + c)*16);
#pragma unroll
        for (int d = 0; d < 4; ++d) {
            const float4 v0 = p0[d]; const float4 v1 = p1[d];
            xs0[(4*d+0)*128+tid] = v0.x; xs0[(4*d+1)*128+tid] = v0.y;
            xs0[(4*d+2)*128+tid] = v0.z; xs0[(4*d+3)*128+tid] = v0.w;
            xs1[(4*d+0)*128+tid] = v1.x; xs1[(4*d+1)*128+tid] = v1.y;
            xs1[(4*d+2)*128+tid] = v1.z; xs1[(4*d+3)*128+tid] = v1.w;
        }
        float4 acc0 = make_float4(0,0,0,0), acc1 = acc0;
        int t3 = 0, t2i = 0;
#pragma unroll 1
        for (int a = 0; a < 16; ++a) {
            const float xa0 = xs0[a*128+tid];
            const float xa1 = xs1[a*128+tid];
            float4 tP0 = T1s[a], tP1 = tP0;
#pragma unroll 1
            for (int b = a; b < 16; ++b) {
                const float xb0 = xs0[b*128+tid];
                const float xb1 = xs1[b*128+tid];
                const float4 c2v = T2s[t2i]; ++t2i;
                float4 tB0 = c2v, tB1 = c2v;
#pragma unroll 4
                for (int cc = b; cc < 16; ++cc) {
                    const float xc0 = xs0[cc*128+tid];
                    const float xc1 = xs1[cc*128+tid];
                    const float4 c3v = T3s[t3]; ++t3;
                    tB0.x = fmaf(c3v.x, xc0, tB0.x); tB0.y = fmaf(c3v.y, xc0, tB0.y);
                    tB0.z = fmaf(c3v.z, xc0, tB0.z); tB0.w = fmaf(c3v.w, xc0, tB0.w);
                    tB1.x = fmaf(c3v.x, xc1, tB1.x); tB1.y = fmaf(c3v.y, xc1, tB1.y);
                    tB1.z = fmaf(c3v.z, xc1, tB1.z); tB1.w = fmaf(c3v.w, xc1, tB1.w);
                }
                tP0.x = fmaf(tB0.x, xb0, tP0.x); tP0.y = fmaf(tB0.y, xb0, tP0.y);
                tP0.z = fmaf(tB0.z, xb0, tP0.z); tP0.w = fmaf(tB0.w, xb0, tP0.w);
                tP1.x = fmaf(tB1.x, xb1, tP1.x); tP1.y = fmaf(tB1.y, xb1, tP1.y);
                tP1.z = fmaf(tB1.z, xb1, tP1.z); tP1.w = fmaf(tB1.w, xb1, tP1.w);
            }
            acc0.x = fmaf(tP0.x, xa0, acc0.x); acc0.y = fmaf(tP0.y, xa0, acc0.y);
            acc0.z = fmaf(tP0.z, xa0, acc0.z); acc0.w = fmaf(tP0.w, xa0, acc0.w);
            acc1.x = fmaf(tP1.x, xa1, acc1.x); acc1.y = fmaf(tP1.y, xa1, acc1.y);
            acc1.z = fmaf(tP1.z, xa1, acc1.z); acc1.w = fmaf(tP1.w, xa1, acc1.w);
        }
        if (act0) {
            float* o = outg + (size_t)n0*512;
            o[c] = acc0.x;
            o[128 + c*3 + 0] = acc0.y; o[128 + c*3 + 1] = acc0.z; o[128 + c*3 + 2] = acc0.w;
        }
        if (act1) {
            float* o = outg + (size_t)n1*512;
            o[c] = acc1.x;
            o[128 + c*3 + 0] = acc1.y; o[128 + c*3 + 1] = acc1.z; o[128 + c*3 + 2] = acc1.w;
        }
    }
}

extern "C" void kernel_launch(void* const* d_in, const int* in_sizes, int n_in,
                              void* d_out, int out_size, void* d_ws, size_t ws_size,
                              hipStream_t stream) {
    const float* x = (const float*)d_in[0];
    const float* y = (const float*)d_in[1];
    const float* U3_0 = (const float*)d_in[2];
    const float* U2_0 = (const float*)d_in[3];
    const float* U1_0 = (const float*)d_in[4];
    const float* W3_0 = (const float*)d_in[5];
    const float* W2_0 = (const float*)d_in[6];
    const float* W1_0 = (const float*)d_in[7];
    const float* U3_1 = (const float*)d_in[8];
    const float* U2_1 = (const float*)d_in[9];
    const float* U1_1 = (const float*)d_in[10];
    const float* W3_1 = (const float*)d_in[11];
    const float* W2_1 = (const float*)d_in[12];
    const float* W1_1 = (const float*)d_in[13];
    float* out = (float*)d_out;
    float* ws = (float*)d_ws;

    prep_sym<<<dim3(PREP_BLOCKS + EN), 256, 0, stream>>>(U3_0, U2_0, U3_1, U2_1, y, ws);
    if (ws_size >= WS_NEED_BYTES) {
        sc_build<<<dim3(NTT/8, EN), 128, 0, stream>>>(ws, (float4*)(ws + TALL_OFF),
                                                      U1_0, U1_1,
                                                      W3_0, W2_0, W1_0, W3_1, W2_1, W1_1);
        sc_apply<<<dim3(CN, EN), 128, 0, stream>>>(x, ws, out);
    } else {
        sc_main_fused<<<dim3(CN, EN), 128, 0, stream>>>(x, U1_0, U1_1,
                                                        W3_0, W2_0, W1_0,
                                                        W3_1, W2_1, W1_1, ws, out);
    }
}